// Round 1
// baseline (335.394 us; speedup 1.0000x reference)
//
#include <hip/hip_runtime.h>
#include <math.h>

// Fully-fused pipeline, one heavyweight kernel + prep + softmax.
// R1 change vs baseline: each 16-series tile is now processed by a WAVE PAIR
// split along conv2 output position q (wave A: q 0..4 -> pool2 windows 0,1;
// wave B: q 5..9 -> windows 2,3). Doubles wave parallelism (2048 -> 4096
// waves, grid 512 -> 1024) with ZERO duplicated work: halves are independent
// through conv1/conv2/pool2, meet once at the LDS transpose tile (disjoint
// 4B words), and split conv3 by output channel (nt3 0-3 / 4-7).
// Also: rolling 16-float x-window (4x float4) instead of 48 live floats --
// same 12 loads per window, ~32 fewer live VGPRs.
//   k0    : w2 [64][32][3] -> w2b bf16 [64][96] (k=d*32+ci); w3 -> w3b bf16
//   k_fused: conv1+pool1 per-lane in EXACT MFMA-A layout -> conv2 MFMA
//     -> bias+relu+pool2 per-lane -> packed bf16 via pair-shared LDS tile
//     -> conv3 GEMM (K=256) -> relu -> logits partials -> butterfly
//     -> per-block partial[1024][3]
//   k_soft: 1 block: logits = sum of 4 partials + bl, softmax -> out [256][3]

typedef __attribute__((ext_vector_type(8))) short bf16x8;
typedef __attribute__((ext_vector_type(4))) float f32x4;

__device__ __forceinline__ ushort f2bf(float f) {
    union { float f; uint u; } c; c.f = f;
    return (ushort)((c.u + 0x7FFFu + ((c.u >> 16) & 1u)) >> 16);   // RNE
}

#define S2 264   // sh2 row stride (ushorts): 528B rows, 16B-aligned

__global__ void k0_prep(const float* __restrict__ w2, ushort* __restrict__ w2b,
                        const float* __restrict__ w3, ushort* __restrict__ w3b) {
    int i = blockIdx.x * 256 + threadIdx.x;
    if (i < 6144) {                     // w2[c][ci][d] -> w2b[c][d*32+ci]
        int c = i / 96, r = i - c * 96;
        int ci = r / 3, d = r - ci * 3;
        w2b[c * 96 + d * 32 + ci] = f2bf(w2[i]);
    }
    int j = i - 6144;
    if (j >= 0 && j < 32768) w3b[j] = f2bf(w3[j]);
}

__global__ __launch_bounds__(256) void k_fused(
    const float* __restrict__ x,     // [32768][1216]
    const float* __restrict__ w1,    // [32][10]
    const float* __restrict__ b1,    // [32]
    const ushort* __restrict__ w2b,  // [64][96]
    const float* __restrict__ b2,    // [64]
    const ushort* __restrict__ w3b,  // [128][256]
    const float* __restrict__ b3,    // [128]
    const float* __restrict__ wl,    // [3][16384]
    float* __restrict__ partials)    // [1024][3]
{
    __shared__ ushort sh2[2 * 16 * S2];     // one 16x256 bf16 tile per wave PAIR
    __shared__ float red[4][3];
    const int wave = threadIdx.x >> 6, lane = threadIdx.x & 63;
    const int lm   = lane & 15, quad = lane >> 4;
    const int half = wave & 1;              // which q-half this wave owns
    const int bn0  = blockIdx.x * 32 + (wave >> 1) * 16;
    const float* xr = x + (size_t)(bn0 + lm) * 1216;

    // hoist this lane's conv1 weights: channels quad*8..quad*8+7
    float wv[8][10], b1v[8];
    #pragma unroll
    for (int h = 0; h < 8; ++h) {
        const float* wr = w1 + (quad * 8 + h) * 10;     // 4 distinct addrs/wave
        #pragma unroll
        for (int kk = 0; kk < 5; ++kk) {
            float2 t = *(const float2*)(wr + 2 * kk);
            wv[h][2*kk] = t.x; wv[h][2*kk+1] = t.y;
        }
        b1v[h] = b1[quad * 8 + h];
    }
    float bias2[4];
    #pragma unroll
    for (int nt = 0; nt < 4; ++nt) bias2[nt] = b2[nt * 16 + lm];

    // ---- conv1 -> conv2 MFMA -> pool2 over this wave's q-half
    // pool2 windows: half0 handles {0,1},{2,3,4}; half1 handles {5,6,7},{8,9}
    f32x4 cur[4];
    #pragma unroll
    for (int nt = 0; nt < 4; ++nt) cur[nt] = (f32x4){-3e38f,-3e38f,-3e38f,-3e38f};
    uint pkh[4][4];                         // 2 packed pooled bf16 windows [nt][r]

    const int q0 = half * 5;
    for (int ql = 0; ql < 5; ++ql) {        // dynamic: keep icache small
        f32x4 acc[4];
        #pragma unroll
        for (int nt = 0; nt < 4; ++nt) acc[nt] = (f32x4){0.f,0.f,0.f,0.f};

        #pragma unroll
        for (int kc = 0; kc < 3; ++kc) {
            const int p = 3 * (q0 + ql) + kc;   // conv1-pooled position 0..29
            const int base = 40 * p - 4;        // 16B-aligned window
            const float4* xp4 = (const float4*)(xr + base);
            // rolling 16-float window [8dt .. 8dt+15]; taps are floats 3..12
            float4 c0 = (base >= 0) ? xp4[0]            // uniform branch
                                    : make_float4(0.f, 0.f, 0.f, 0.f); // p==0 pad
            float4 c1 = xp4[1], c2 = xp4[2], c3 = xp4[3];
            float mx[8];
            #pragma unroll
            for (int h = 0; h < 8; ++h) mx[h] = 0.f;    // relu folded into pool
            #pragma unroll
            for (int dt = 0; dt < 5; ++dt) {            // conv1 K=10 s=8 p=1 + pool5
                const float xv[10] = {c0.w, c1.x, c1.y, c1.z, c1.w,
                                      c2.x, c2.y, c2.z, c2.w, c3.x};
                float a[8];
                #pragma unroll
                for (int h = 0; h < 8; ++h) a[h] = b1v[h];
                #pragma unroll
                for (int k = 0; k < 10; ++k)
                    #pragma unroll
                    for (int h = 0; h < 8; ++h)
                        a[h] = fmaf(wv[h][k], xv[k], a[h]);
                #pragma unroll
                for (int h = 0; h < 8; ++h) mx[h] = fmaxf(mx[h], a[h]);
                if (dt < 4) {                           // roll by 8 floats
                    c0 = c2; c1 = c3;
                    c2 = xp4[2*dt + 4]; c3 = xp4[2*dt + 5];
                }
            }
            union { ushort u[8]; bf16x8 v; } af;
            #pragma unroll
            for (int h = 0; h < 8; ++h) af.u[h] = f2bf(mx[h]);
            #pragma unroll
            for (int nt = 0; nt < 4; ++nt) {   // w2b frags from L1 (12KB hot)
                bf16x8 bfr = *(const bf16x8*)(w2b + (nt*16+lm)*96 + kc*32 + quad*8);
                acc[nt] = __builtin_amdgcn_mfma_f32_16x16x32_bf16(af.v, bfr, acc[nt], 0, 0, 0);
            }
        }

        // pool2 bookkeeping (wave-uniform):
        // half0: fresh at ql 0,2; close at ql 1 (slot0), 4 (slot1)
        // half1: fresh at ql 0,3; close at ql 2 (slot0), 4 (slot1)
        const bool fresh = (ql == 0) || (ql == 2 + half);
        #pragma unroll
        for (int nt = 0; nt < 4; ++nt)
            #pragma unroll
            for (int r = 0; r < 4; ++r)
                cur[nt][r] = fresh ? acc[nt][r] : fmaxf(cur[nt][r], acc[nt][r]);

        if (ql == 1 + half || ql == 4) {        // window end
            const int w = (ql == 4) ? 1 : 0;    // slot within this wave's uint
            #pragma unroll
            for (int nt = 0; nt < 4; ++nt)
                #pragma unroll
                for (int r = 0; r < 4; ++r) {
                    float f = fmaxf(cur[nt][r] + bias2[nt], 0.f);
                    uint hb = (uint)f2bf(f);
                    if (w == 0) pkh[nt][r]  = hb;
                    else        pkh[nt][r] |= hb << 16;
                }
        }
    }

    // ---- transpose via pair-shared LDS: rows = series, k = c2*4 + window
    // wave half writes windows 2*half, 2*half+1 -> disjoint 4B words
    ushort* shw = sh2 + (wave >> 1) * 16 * S2;
    #pragma unroll
    for (int nt = 0; nt < 4; ++nt)
        #pragma unroll
        for (int r = 0; r < 4; ++r)
            *(uint*)(shw + (quad*4 + r) * S2 + (nt*16 + lm) * 4 + half * 2) = pkh[nt][r];
    __syncthreads();

    // ---- conv3 GEMM (16 series x 64 cols per wave, K=256) + logits partials
    bf16x8 afr[8];
    #pragma unroll
    for (int kc = 0; kc < 8; ++kc)          // A-frag: row lm, 16B contiguous
        afr[kc] = *(const bf16x8*)(shw + lm * S2 + kc * 32 + quad * 8);

    const int node0 = bn0 & 127;
    const float* wlr = wl + (node0 + quad * 4) * 128 + lm;
    float a0 = 0.f, a1 = 0.f, a2 = 0.f;
    for (int t3 = 0; t3 < 4; ++t3) {        // this wave's channel half
        const int nt3 = half * 4 + t3;
        f32x4 acc3 = (f32x4){0.f, 0.f, 0.f, 0.f};
        const ushort* bb = w3b + (size_t)(nt3 * 16 + lm) * 256 + quad * 8;
        #pragma unroll
        for (int kc = 0; kc < 8; ++kc) {
            bf16x8 bf3 = *(const bf16x8*)(bb + kc * 32);
            acc3 = __builtin_amdgcn_mfma_f32_16x16x32_bf16(afr[kc], bf3, acc3, 0, 0, 0);
        }
        const float b3v = b3[nt3 * 16 + lm];
        #pragma unroll
        for (int r = 0; r < 4; ++r) {       // feat value, never materialized
            float f = fmaxf(acc3[r] + b3v, 0.f);
            const float* wp = wlr + r * 128 + nt3 * 16;
            a0 = fmaf(f, wp[0],     a0);
            a1 = fmaf(f, wp[16384], a1);
            a2 = fmaf(f, wp[32768], a2);
        }
    }

    #pragma unroll
    for (int off = 32; off > 0; off >>= 1) {
        a0 += __shfl_xor(a0, off);
        a1 += __shfl_xor(a1, off);
        a2 += __shfl_xor(a2, off);
    }
    if (lane == 0) { red[wave][0] = a0; red[wave][1] = a1; red[wave][2] = a2; }
    __syncthreads();
    if (threadIdx.x < 3) {
        float s = red[0][threadIdx.x] + red[1][threadIdx.x]
                + red[2][threadIdx.x] + red[3][threadIdx.x];
        partials[blockIdx.x * 3 + threadIdx.x] = s;
    }
}

// logits = partials[4b..4b+3] + bl -> softmax
__global__ void k_soft(const float* __restrict__ partials,
                       const float* __restrict__ bl,
                       float* __restrict__ out) {
    const int b = threadIdx.x;      // 256 batches, 1 block
    float l0 = bl[0], l1 = bl[1], l2 = bl[2];
    #pragma unroll
    for (int j = 0; j < 4; ++j) {
        const float* pr = partials + (4*b + j) * 3;
        l0 += pr[0]; l1 += pr[1]; l2 += pr[2];
    }
    float m  = fmaxf(l0, fmaxf(l1, l2));
    float e0 = expf(l0 - m), e1 = expf(l1 - m), e2 = expf(l2 - m);
    float s  = e0 + e1 + e2;
    out[b*3+0] = e0 / s; out[b*3+1] = e1 / s; out[b*3+2] = e2 / s;
}

extern "C" void kernel_launch(void* const* d_in, const int* in_sizes, int n_in,
                              void* d_out, int out_size, void* d_ws, size_t ws_size,
                              hipStream_t stream) {
    const float* x  = (const float*)d_in[0];
    const float* w1 = (const float*)d_in[1];
    const float* b1 = (const float*)d_in[2];
    const float* w2 = (const float*)d_in[3];
    const float* b2 = (const float*)d_in[4];
    const float* w3 = (const float*)d_in[5];
    const float* b3 = (const float*)d_in[6];
    const float* wl = (const float*)d_in[7];
    const float* bl = (const float*)d_in[8];
    float* out = (float*)d_out;

    // tiny ws: w2b 12KB | w3b 64KB | partials 12KB
    ushort* w2b      = (ushort*)d_ws;
    ushort* w3b      = (ushort*)((char*)d_ws + 16384);
    float*  partials = (float*)((char*)d_ws + 16384 + 65536);

    k0_prep<<<152, 256, 0, stream>>>(w2, w2b, w3, w3b);
    k_fused<<<1024, 256, 0, stream>>>(x, w1, b1, w2b, b2, w3b, b3, wl, partials);
    k_soft<<<1, 256, 0, stream>>>(partials, bl, out);
}